// Round 2
// baseline (667.850 us; speedup 1.0000x reference)
//
#include <hip/hip_runtime.h>
#include <hip/hip_bf16.h>

// ---------- types ----------
typedef __bf16 bf16x8 __attribute__((ext_vector_type(8)));
typedef __bf16 bf16x4 __attribute__((ext_vector_type(4)));
typedef float  f32x4  __attribute__((ext_vector_type(4)));

__device__ __forceinline__ f32x4 mfma16(bf16x8 a, bf16x8 b, f32x4 c) {
    return __builtin_amdgcn_mfma_f32_16x16x32_bf16(a, b, c, 0, 0, 0);
}
__device__ __forceinline__ float silu_f(float v) { return v / (1.f + __expf(-v)); }
__device__ __forceinline__ float softplus_fast(float v) {
    float r = __logf(1.f + __expf(v));
    return v > 15.f ? v : r;   // exp overflow guard
}

// Problem constants
#define CC 192        // d_model
#define DI 384        // d_inner
#define LL 16384      // H*W
#define HH 128
#define WW 128

// ---------- K0: weight prep (transpose + bf16 cast) ----------
// wt_in [768][192], wt_x [32][384], wt_dt [384][16], wt_out [192][384]
__global__ void k0_prep(const float* __restrict__ w_in, const float* __restrict__ w_x,
                        const float* __restrict__ w_dt, const float* __restrict__ w_out,
                        __bf16* __restrict__ wt_in, __bf16* __restrict__ wt_x,
                        __bf16* __restrict__ wt_dt, __bf16* __restrict__ wt_out) {
    int tid = blockIdx.x * blockDim.x + threadIdx.x;
    int nth = gridDim.x * blockDim.x;
    for (int i = tid; i < 768 * 192; i += nth) { int n = i / 192, k = i % 192; wt_in[i] = (__bf16)w_in[k * 768 + n]; }
    for (int i = tid; i < 32 * 384;  i += nth) { int n = i / 384, k = i % 384; wt_x[i]  = (__bf16)w_x[k * 32 + n]; }
    for (int i = tid; i < 384 * 16;  i += nth) { int ch = i / 16, k = i % 16;  wt_dt[i] = (__bf16)w_dt[k * 384 + ch]; }
    for (int i = tid; i < 192 * 384; i += nth) { int n = i / 384, k = i % 384; wt_out[i] = (__bf16)w_out[k * 192 + n]; }
}

// ---------- K1: x_proj GEMM  [M,192]@[192,768] -> x_inner bf16, silu(z) bf16 ----------
// 64 tokens/block, 16 rows/wave, single wave-private LDS bounce (intra-wave DS pipe is
// in-order -> no double buffer, no s_barrier anywhere). LDS 8704 B, VGPR target <=64
// -> __launch_bounds__(256,8): 8 blocks/CU, 32 waves/CU; grid 2048 = one residency round.
__global__ __launch_bounds__(256, 8) void k1_proj(
        const float* __restrict__ x, const __bf16* __restrict__ wt_in,
        __bf16* __restrict__ xin, __bf16* __restrict__ zsb) {
    // [4 waves][16 rows][stride 68] bf16 = 8704 B; stride 68: write banks per quad
    // {8q..8q+7} (2 lanes/bank same-dword -> free), b64 drain pattern measured 0-conflict.
    __shared__ __attribute__((aligned(16))) __bf16 wb[4 * 16 * 68];
    const int tid = threadIdx.x;
    const int lane = tid & 63, wv = tid >> 6;
    const int lq = lane & 15, quad = lane >> 4;
    const long mbase = (long)blockIdx.x * 64;
    __bf16* bb = wb + wv * (16 * 68);

    // A-fragments direct from global f32 x, bf16 cvt in-reg (rows touched exactly once;
    // per instruction the 4 quads cover 128 contiguous B per row).
    bf16x8 af[6];
    {
        const float* xr = x + (mbase + wv * 16 + lq) * CC;
#pragma unroll
        for (int ks = 0; ks < 6; ks++) {
            float4 v0 = *(const float4*)(xr + ks * 32 + quad * 8);
            float4 v1 = *(const float4*)(xr + ks * 32 + quad * 8 + 4);
            bf16x8 t;
            t[0] = (__bf16)v0.x; t[1] = (__bf16)v0.y; t[2] = (__bf16)v0.z; t[3] = (__bf16)v0.w;
            t[4] = (__bf16)v1.x; t[5] = (__bf16)v1.y; t[6] = (__bf16)v1.z; t[7] = (__bf16)v1.w;
            af[ks] = t;
        }
    }

    for (int nc = 0; nc < 12; nc++) {
        f32x4 A0[4];
#pragma unroll
        for (int nt = 0; nt < 4; nt++) {
            A0[nt] = (f32x4){0.f, 0.f, 0.f, 0.f};
#pragma unroll
            for (int ks = 0; ks < 6; ks++) {
                bf16x8 bf = *(const bf16x8*)(wt_in + (long)(nc * 64 + nt * 16 + lq) * CC + ks * 32 + quad * 8);
                A0[nt] = mfma16(af[ks], bf, A0[nt]);
            }
        }
        const bool isz = (nc >= 6);
#pragma unroll
        for (int nt = 0; nt < 4; nt++) {
#pragma unroll
            for (int r = 0; r < 4; r++) {
                float v0 = A0[nt][r];
                if (isz) v0 = silu_f(v0);
                bb[(quad * 4 + r) * 68 + nt * 16 + lq] = (__bf16)v0;
            }
        }
        // intra-wave ordering only: DS pipe is in-order per wave; wave_barrier pins the
        // compiler's program order (no runtime cost, no s_barrier).
        __builtin_amdgcn_wave_barrier();
        __bf16* dst = isz ? zsb : xin;
        const int chb = (isz ? nc - 6 : nc) * 64;
#pragma unroll
        for (int k = 0; k < 2; k++) {
            int u = lane + k * 64;
            int row = u >> 3, c8 = u & 7;
            unsigned long long lo = *(const unsigned long long*)(&bb[row * 68 + c8 * 8]);
            unsigned long long hi = *(const unsigned long long*)(&bb[row * 68 + c8 * 8 + 4]);
            ulonglong2 val; val.x = lo; val.y = hi;
            *(ulonglong2*)(dst + (mbase + wv * 16 + row) * DI + chb + c8 * 8) = val;
        }
        __builtin_amdgcn_wave_barrier();  // keep nc+1's writes ordered after this nc's reads
    }
}

// ---------- K3: fused conv+ssm: depthwise 3x3+silu on the fly, then x_ssm MFMA,
// dt MFMA, epilogue, LN, out-GEMM, transposed store. k2 is GONE: the xc 100 MB
// write+read round-trip is eliminated; xin 9-tap gather hits L2/L3 (xin < L3).
// 64 consecutive tokens/block (half an image row -> h uniform); grid 2048; 256 thr.
// LDS = 81152 B -> 2 blocks/CU. Conv weights stage into the dts region (dead till P3a).
__global__ __launch_bounds__(256, 2) void k3_ssm(
        const __bf16* __restrict__ xin, const __bf16* __restrict__ zsb,
        const __bf16* __restrict__ wtx, const __bf16* __restrict__ wtdt,
        const __bf16* __restrict__ wtout, const float* __restrict__ wconv,
        const float* __restrict__ bconv, const float* __restrict__ bdt,
        const float* __restrict__ dskip, const float* __restrict__ gamma,
        const float* __restrict__ beta, float* __restrict__ out) {
    __shared__ __attribute__((aligned(16))) float smem0[13056];   // 52224 B: xcb bf16[64][392] / otile f32[192][68]
    __shared__ __attribute__((aligned(16))) __bf16 dts[64 * 200]; // 25600 B: dt half-tile; P0: conv weights
    __shared__ __attribute__((aligned(16))) __bf16 bss[64 * 24];  // 3072 B
    __shared__ float bcarr[64];                                   // 256 B
    __bf16* xcb = (__bf16*)smem0;
    float* otile = smem0;

    const int tid = threadIdx.x;
    const int lane = tid & 63, wv = tid >> 6;
    const int lq = lane & 15, quad = lane >> 4;
    const int t0g = blockIdx.x * 64;

    // P0a: stage conv weights into dts region (wcvs [9][384] + bcvs [384] = 15360 B)
    float* wcvs = (float*)dts;
    float* bcvs = wcvs + 9 * 384;
    for (int u = tid; u < 9 * 384; u += 256) { int ch = u / 9, tap = u % 9; wcvs[tap * 384 + ch] = wconv[u]; }
    for (int u = tid; u < 384; u += 256) bcvs[u] = bconv[u];
    __syncthreads();

    // P0b: depthwise 3x3 conv + bias + silu, straight from xin -> xcb tile
    const int hblk = (t0g & (LL - 1)) >> 7;   // uniform per block (64 tokens = half row)
    const int w0 = t0g & 127;                 // 0 or 64
#pragma unroll
    for (int k = 0; k < 12; k++) {
        int u = tid + k * 256;
        int t = u / 48, c8 = u % 48;
        long tok = t0g + t;
        float acc[8];
        float4 b0 = *(const float4*)(bcvs + c8 * 8);
        float4 b1 = *(const float4*)(bcvs + c8 * 8 + 4);
        acc[0] = b0.x; acc[1] = b0.y; acc[2] = b0.z; acc[3] = b0.w;
        acc[4] = b1.x; acc[5] = b1.y; acc[6] = b1.z; acc[7] = b1.w;
#pragma unroll
        for (int dy = -1; dy <= 1; dy++) {
            int h2 = hblk + dy;
            if (h2 < 0 || h2 >= HH) continue;   // block-uniform branch
#pragma unroll
            for (int dx = -1; dx <= 1; dx++) {
                int w2 = w0 + t + dx;
                if (w2 < 0 || w2 >= WW) continue;
                bf16x8 v = *(const bf16x8*)(xin + (tok + dy * WW + dx) * (long)DI + c8 * 8);
                const float* wp = &wcvs[((dy + 1) * 3 + (dx + 1)) * 384 + c8 * 8];
#pragma unroll
                for (int j = 0; j < 8; j++) acc[j] += (float)v[j] * wp[j];
            }
        }
        bf16x8 r;
#pragma unroll
        for (int j = 0; j < 8; j++) r[j] = (__bf16)silu_f(acc[j]);
        *(bf16x8*)(&xcb[t * 392 + c8 * 8]) = r;
    }
    __syncthreads();

    // P2: x_ssm = xc @ w_x (K=384, N=32); bc = sum_s B*C; stash B_ssm bf16
    {
        f32x4 aB = {0.f, 0.f, 0.f, 0.f}, aC = {0.f, 0.f, 0.f, 0.f};
#pragma unroll
        for (int ks = 0; ks < 12; ks++) {
            bf16x8 a = *(const bf16x8*)(&xcb[(wv * 16 + lq) * 392 + ks * 32 + quad * 8]);
            bf16x8 b0 = *(const bf16x8*)(wtx + lq * 384 + ks * 32 + quad * 8);
            bf16x8 b1 = *(const bf16x8*)(wtx + (16 + lq) * 384 + ks * 32 + quad * 8);
            aB = mfma16(a, b0, aB);
            aC = mfma16(a, b1, aC);
        }
        float p0 = aB[0] * aC[0], p1 = aB[1] * aC[1], p2 = aB[2] * aC[2], p3 = aB[3] * aC[3];
#pragma unroll
        for (int m = 1; m < 16; m <<= 1) {
            p0 += __shfl_xor(p0, m, 64);
            p1 += __shfl_xor(p1, m, 64);
            p2 += __shfl_xor(p2, m, 64);
            p3 += __shfl_xor(p3, m, 64);
        }
        int trow = wv * 16 + quad * 4;
        if (lq == 0) { bcarr[trow] = p0; bcarr[trow + 1] = p1; bcarr[trow + 2] = p2; bcarr[trow + 3] = p3; }
        bss[(trow + 0) * 24 + lq] = (__bf16)aB[0];
        bss[(trow + 1) * 24 + lq] = (__bf16)aB[1];
        bss[(trow + 2) * 24 + lq] = (__bf16)aB[2];
        bss[(trow + 3) * 24 + lq] = (__bf16)aB[3];
    }
    __syncthreads();

    bf16x8 zero8;
#pragma unroll
    for (int j = 0; j < 8; j++) zero8[j] = (__bf16)0.f;

    // A-fragments for dt MFMA (K=16 lives in quads 0,1; quads 2,3 feed zeros)
    bf16x8 aA[4];
#pragma unroll
    for (int mt = 0; mt < 4; mt++)
        aA[mt] = (quad < 2) ? *(const bf16x8*)(&bss[(mt * 16 + lq) * 24 + quad * 8]) : zero8;

    const int te = tid >> 2, part = tid & 3;     // epilogue mapping
    const long tok = t0g + te;
    float s1 = 0.f, s2 = 0.f;

    for (int h = 0; h < 2; h++) {
        // P3a: dt MFMA for channels h*192 .. h*192+191 (3 n-tiles per wave)
        f32x4 dacc[3][4];
        float bdtv[3];
#pragma unroll
        for (int j = 0; j < 3; j++) {
            int chg = h * 192 + (wv * 3 + j) * 16 + lq;
            bf16x8 bf = (quad < 2) ? *(const bf16x8*)(wtdt + (long)chg * 16 + quad * 8) : zero8;
            bdtv[j] = bdt[chg];
#pragma unroll
            for (int mt = 0; mt < 4; mt++) {
                f32x4 z4 = {0.f, 0.f, 0.f, 0.f};
                dacc[j][mt] = mfma16(aA[mt], bf, z4);
            }
        }
        // scatter dt(+b_dt) to LDS (stride 200 -> conflict-free)
#pragma unroll
        for (int j = 0; j < 3; j++)
#pragma unroll
            for (int mt = 0; mt < 4; mt++)
#pragma unroll
                for (int r = 0; r < 4; r++)
                    dts[(mt * 16 + quad * 4 + r) * 200 + (wv * 3 + j) * 16 + lq] =
                        (__bf16)(dacc[j][mt][r] + bdtv[j]);
        __syncthreads();

        // epilogue: y = (softplus(dt)*bc + xc*dskip) * z ; accumulate LN stats
#pragma unroll
        for (int g = 0; g < 6; g++) {
            const int chl = part * 48 + g * 8;
            const int chg = h * 192 + chl;
            bf16x8 d8 = *(const bf16x8*)(&dts[te * 200 + chl]);
            bf16x8 xc8 = *(const bf16x8*)(&xcb[te * 392 + chg]);
            bf16x8 z8 = *(const bf16x8*)(zsb + tok * DI + chg);
            float4 d0 = *(const float4*)(dskip + chg);
            float4 d1 = *(const float4*)(dskip + chg + 4);
            float ds[8] = {d0.x, d0.y, d0.z, d0.w, d1.x, d1.y, d1.z, d1.w};
            const float bcv = bcarr[te];
#pragma unroll
            for (int j = 0; j < 8; j++) {
                float dtv = softplus_fast((float)d8[j]);
                float yv = (dtv * bcv + (float)xc8[j] * ds[j]) * (float)z8[j];
                s1 += yv; s2 += yv * yv;
                xc8[j] = (__bf16)yv;
            }
            *(bf16x8*)(&xcb[te * 392 + chg]) = xc8;
        }
        __syncthreads();  // dts reads done before next half's scatter
    }

    // LN (thread owns its 12 channel-groups across both halves)
    {
        s1 += __shfl_xor(s1, 1, 64); s2 += __shfl_xor(s2, 1, 64);
        s1 += __shfl_xor(s1, 2, 64); s2 += __shfl_xor(s2, 2, 64);
        float mu = s1 * (1.f / 384.f);
        float var = s2 * (1.f / 384.f) - mu * mu;
        float rstd = rsqrtf(var + 1e-5f);
#pragma unroll
        for (int gg = 0; gg < 12; gg++) {
            const int h2 = gg / 6, g6 = gg % 6;
            const int ch = h2 * 192 + part * 48 + g6 * 8;
            bf16x8 v = *(const bf16x8*)(&xcb[te * 392 + ch]);
            float4 g0 = *(const float4*)(gamma + ch);
            float4 g1 = *(const float4*)(gamma + ch + 4);
            float4 be0 = *(const float4*)(beta + ch);
            float4 be1 = *(const float4*)(beta + ch + 4);
            float gm[8] = {g0.x, g0.y, g0.z, g0.w, g1.x, g1.y, g1.z, g1.w};
            float bt[8] = {be0.x, be0.y, be0.z, be0.w, be1.x, be1.y, be1.z, be1.w};
#pragma unroll
            for (int j = 0; j < 8; j++) v[j] = (__bf16)(((float)v[j] - mu) * rstd * gm[j] + bt[j]);
            *(bf16x8*)(&xcb[te * 392 + ch]) = v;
        }
    }
    __syncthreads();

    // P5: out GEMM y[64,384] @ wt_out^T -> [64,192]; waves split N (3 n-tiles each)
    {
        f32x4 acc[3][4];
#pragma unroll
        for (int j = 0; j < 3; j++)
#pragma unroll
            for (int mt = 0; mt < 4; mt++) acc[j][mt] = (f32x4){0.f, 0.f, 0.f, 0.f};
#pragma unroll
        for (int ks = 0; ks < 12; ks++) {
            bf16x8 bfr[3];
#pragma unroll
            for (int j = 0; j < 3; j++) {
                int c = (wv * 3 + j) * 16 + lq;
                bfr[j] = *(const bf16x8*)(wtout + (long)c * 384 + ks * 32 + quad * 8);
            }
#pragma unroll
            for (int mt = 0; mt < 4; mt++) {
                bf16x8 afr = *(const bf16x8*)(&xcb[(mt * 16 + lq) * 392 + ks * 32 + quad * 8]);
#pragma unroll
                for (int j = 0; j < 3; j++) acc[j][mt] = mfma16(afr, bfr[j], acc[j][mt]);
            }
        }
        __syncthreads();  // all y-reads done; otile overwrites xcb region
#pragma unroll
        for (int j = 0; j < 3; j++) {
            int c = (wv * 3 + j) * 16 + lq;
#pragma unroll
            for (int mt = 0; mt < 4; mt++)
#pragma unroll
                for (int r = 0; r < 4; r++)
                    otile[c * 68 + mt * 16 + quad * 4 + r] = acc[j][mt][r];
        }
    }
    __syncthreads();

    // P6: store out[b][c][l]: 256 B contiguous per channel
    {
        const int bimg = t0g >> 14;
        const int l0 = t0g & (LL - 1);
#pragma unroll
        for (int k = 0; k < 12; k++) {
            int u = tid + k * 256;       // 3072 units = 192 ch x 16 float4
            int c = u >> 4, j = u & 15;
            float4 v = *(const float4*)(&otile[c * 68 + j * 4]);
            *(float4*)(out + ((long)(bimg * CC + c)) * LL + l0 + j * 4) = v;
        }
    }
}

// ---------- launch ----------
extern "C" void kernel_launch(void* const* d_in, const int* in_sizes, int n_in,
                              void* d_out, int out_size, void* d_ws, size_t ws_size,
                              hipStream_t stream) {
    (void)in_sizes; (void)n_in; (void)out_size; (void)ws_size;
    const float* x      = (const float*)d_in[0];
    const float* w_in   = (const float*)d_in[1];
    const float* w_conv = (const float*)d_in[2];
    const float* b_conv = (const float*)d_in[3];
    const float* w_x    = (const float*)d_in[4];
    const float* w_dt   = (const float*)d_in[5];
    const float* b_dt   = (const float*)d_in[6];
    const float* D_skip = (const float*)d_in[7];
    const float* w_out  = (const float*)d_in[8];
    const float* gamma  = (const float*)d_in[9];
    const float* beta   = (const float*)d_in[10];
    float* out = (float*)d_out;

    char* ws = (char*)d_ws;
    __bf16* wt_in  = (__bf16*)(ws);                       // 294912 B
    __bf16* wt_x   = (__bf16*)(ws + 294912);              // 24576 B
    __bf16* wt_dt  = (__bf16*)(ws + 319488);              // 12288 B
    __bf16* wt_out = (__bf16*)(ws + 331776);              // 147456 B
    __bf16* xin    = (__bf16*)(ws + 479232);              // 100663296 B
    __bf16* zsb    = (__bf16*)(ws + 479232 + 100663296);  // 100663296 B

    k0_prep<<<96, 256, 0, stream>>>(w_in, w_x, w_dt, w_out, wt_in, wt_x, wt_dt, wt_out);
    k1_proj<<<2048, 256, 0, stream>>>(x, wt_in, xin, zsb);
    k3_ssm<<<2048, 256, 0, stream>>>(xin, zsb, wt_x, wt_dt, wt_out, w_conv, b_conv,
                                     b_dt, D_skip, gamma, beta, out);
}

// Round 3
// 551.482 us; speedup vs baseline: 1.2110x; 1.2110x over previous
//
#include <hip/hip_runtime.h>
#include <hip/hip_bf16.h>

// ---------- types ----------
typedef __bf16 bf16x8 __attribute__((ext_vector_type(8)));
typedef __bf16 bf16x4 __attribute__((ext_vector_type(4)));
typedef float  f32x4  __attribute__((ext_vector_type(4)));

__device__ __forceinline__ f32x4 mfma16(bf16x8 a, bf16x8 b, f32x4 c) {
    return __builtin_amdgcn_mfma_f32_16x16x32_bf16(a, b, c, 0, 0, 0);
}
__device__ __forceinline__ float silu_f(float v) { return v / (1.f + __expf(-v)); }
__device__ __forceinline__ float softplus_fast(float v) {
    float r = __logf(1.f + __expf(v));
    return v > 15.f ? v : r;   // exp overflow guard
}

// Problem constants
#define CC 192        // d_model
#define DI 384        // d_inner
#define LL 16384      // H*W
#define HH 128
#define WW 128

// ---------- K0: weight prep (transpose + bf16 cast) ----------
// wt_in [768][192], wt_x [32][384], wt_dt [384][16], wt_out [192][384]
__global__ void k0_prep(const float* __restrict__ w_in, const float* __restrict__ w_x,
                        const float* __restrict__ w_dt, const float* __restrict__ w_out,
                        __bf16* __restrict__ wt_in, __bf16* __restrict__ wt_x,
                        __bf16* __restrict__ wt_dt, __bf16* __restrict__ wt_out) {
    int tid = blockIdx.x * blockDim.x + threadIdx.x;
    int nth = gridDim.x * blockDim.x;
    for (int i = tid; i < 768 * 192; i += nth) { int n = i / 192, k = i % 192; wt_in[i] = (__bf16)w_in[k * 768 + n]; }
    for (int i = tid; i < 32 * 384;  i += nth) { int n = i / 384, k = i % 384; wt_x[i]  = (__bf16)w_x[k * 32 + n]; }
    for (int i = tid; i < 384 * 16;  i += nth) { int ch = i / 16, k = i % 16;  wt_dt[i] = (__bf16)w_dt[k * 384 + ch]; }
    for (int i = tid; i < 192 * 384; i += nth) { int n = i / 384, k = i % 384; wt_out[i] = (__bf16)w_out[k * 192 + n]; }
}

// ---------- K1: x_proj GEMM  [M,192]@[192,768] -> x_inner bf16, silu(z) bf16 ----------
// R1 structure (128 tok/block, wave-private double bounce, zero s_barrier) + explicit
// rolling B-prefetch: flattened (nt,ks) loop keeps 6 B-fragments in flight so each L2
// load is issued ~12 MFMAs before use. VGPR ~120 <= 128 cap (bounds(256,4)).
__global__ __launch_bounds__(256, 4) void k1_proj(
        const float* __restrict__ x, const __bf16* __restrict__ wt_in,
        __bf16* __restrict__ xin, __bf16* __restrict__ zsb) {
    // [4 waves][2 bufs][32 rows][stride 68] bf16 = 34816 B -> 4 blocks/CU
    __shared__ __attribute__((aligned(16))) __bf16 wb[4 * 2 * 32 * 68];
    const int tid = threadIdx.x;
    const int lane = tid & 63, wv = tid >> 6;
    const int lq = lane & 15, quad = lane >> 4;
    const long mbase = (long)blockIdx.x * 128;
    __bf16* wbase = wb + wv * (2 * 32 * 68);

    // A-fragments direct from global f32 x, bf16 cvt in-reg (rows touched exactly once).
    bf16x8 af[2][6];
#pragma unroll
    for (int mt = 0; mt < 2; mt++) {
        const float* xr = x + (mbase + wv * 32 + mt * 16 + lq) * CC;
#pragma unroll
        for (int ks = 0; ks < 6; ks++) {
            float4 v0 = *(const float4*)(xr + ks * 32 + quad * 8);
            float4 v1 = *(const float4*)(xr + ks * 32 + quad * 8 + 4);
            bf16x8 t;
            t[0] = (__bf16)v0.x; t[1] = (__bf16)v0.y; t[2] = (__bf16)v0.z; t[3] = (__bf16)v0.w;
            t[4] = (__bf16)v1.x; t[5] = (__bf16)v1.y; t[6] = (__bf16)v1.z; t[7] = (__bf16)v1.w;
            af[mt][ks] = t;
        }
    }

    for (int nc = 0; nc < 12; nc++) {
        const __bf16* bnc = wt_in + (long)(nc * 64 + lq) * CC + quad * 8;
        f32x4 A0[4], A1[4];
#pragma unroll
        for (int nt = 0; nt < 4; nt++) {
            A0[nt] = (f32x4){0.f, 0.f, 0.f, 0.f};
            A1[nt] = (f32x4){0.f, 0.f, 0.f, 0.f};
        }
        // rolling 6-deep B prefetch over flattened i = nt*6 + ks
        bf16x8 bp[6];
#pragma unroll
        for (int i = 0; i < 6; i++)
            bp[i] = *(const bf16x8*)(bnc + (long)(i / 6) * 16 * CC + (i % 6) * 32);
#pragma unroll
        for (int i = 0; i < 24; i++) {
            const int nt = i / 6, ks = i % 6;
            bf16x8 bcur = bp[i % 6];
            const int i2 = i + 6;
            if (i2 < 24)
                bp[i % 6] = *(const bf16x8*)(bnc + (long)(i2 / 6) * 16 * CC + (i2 % 6) * 32);
            A0[nt] = mfma16(af[0][ks], bcur, A0[nt]);
            A1[nt] = mfma16(af[1][ks], bcur, A1[nt]);
        }
        const bool isz = (nc >= 6);
        __bf16* bb = wbase + (nc & 1) * (32 * 68);
#pragma unroll
        for (int nt = 0; nt < 4; nt++) {
#pragma unroll
            for (int r = 0; r < 4; r++) {
                float v0 = A0[nt][r], v1 = A1[nt][r];
                if (isz) { v0 = silu_f(v0); v1 = silu_f(v1); }
                bb[(quad * 4 + r) * 68 + nt * 16 + lq] = (__bf16)v0;
                bb[(16 + quad * 4 + r) * 68 + nt * 16 + lq] = (__bf16)v1;
            }
        }
        // intra-wave ordering only: DS pipe is in-order per wave.
        __builtin_amdgcn_wave_barrier();
        __bf16* dst = isz ? zsb : xin;
        const int chb = (isz ? nc - 6 : nc) * 64;
#pragma unroll
        for (int k = 0; k < 4; k++) {
            int u = lane + k * 64;
            int row = u >> 3, c8 = u & 7;
            unsigned long long lo = *(const unsigned long long*)(&bb[row * 68 + c8 * 8]);
            unsigned long long hi = *(const unsigned long long*)(&bb[row * 68 + c8 * 8 + 4]);
            ulonglong2 val; val.x = lo; val.y = hi;
            *(ulonglong2*)(dst + (mbase + wv * 32 + row) * DI + chb + c8 * 8) = val;
        }
        __builtin_amdgcn_wave_barrier();  // keep nc+2's writes ordered after this nc's reads
    }
}

// ---------- K3: fused conv+ssm (k2 eliminated). 64 tokens/block; grid 2048.
// LDS 81152 B -> 2 blocks/CU (VGPR cap 256/wave at 2 waves/SIMD -> room for prefetch).
// NEW: z (gate) tile prefetched into 12 bf16x8 regs at kernel start -- these are cold
// HBM reads (~600-900 cyc) previously issued inside the epilogue right before use.
__global__ __launch_bounds__(256, 2) void k3_ssm(
        const __bf16* __restrict__ xin, const __bf16* __restrict__ zsb,
        const __bf16* __restrict__ wtx, const __bf16* __restrict__ wtdt,
        const __bf16* __restrict__ wtout, const float* __restrict__ wconv,
        const float* __restrict__ bconv, const float* __restrict__ bdt,
        const float* __restrict__ dskip, const float* __restrict__ gamma,
        const float* __restrict__ beta, float* __restrict__ out) {
    __shared__ __attribute__((aligned(16))) float smem0[13056];   // 52224 B: xcb bf16[64][392] / otile f32[192][68]
    __shared__ __attribute__((aligned(16))) __bf16 dts[64 * 200]; // 25600 B: dt half-tile; P0: conv weights
    __shared__ __attribute__((aligned(16))) __bf16 bss[64 * 24];  // 3072 B
    __shared__ float bcarr[64];                                   // 256 B
    __bf16* xcb = (__bf16*)smem0;
    float* otile = smem0;

    const int tid = threadIdx.x;
    const int lane = tid & 63, wv = tid >> 6;
    const int lq = lane & 15, quad = lane >> 4;
    const int t0g = blockIdx.x * 64;

    const int te = tid >> 2, part = tid & 3;     // epilogue mapping
    const long tok = t0g + te;

    // Z-prefetch: 12 bf16x8 (48 VGPR) issued now, consumed in the epilogue 4 phases later.
    bf16x8 zpre[12];
#pragma unroll
    for (int h = 0; h < 2; h++)
#pragma unroll
        for (int g = 0; g < 6; g++)
            zpre[h * 6 + g] = *(const bf16x8*)(zsb + tok * DI + h * 192 + part * 48 + g * 8);

    // P0a: stage conv weights into dts region (wcvs [9][384] + bcvs [384] = 15360 B)
    float* wcvs = (float*)dts;
    float* bcvs = wcvs + 9 * 384;
    for (int u = tid; u < 9 * 384; u += 256) { int ch = u / 9, tap = u % 9; wcvs[tap * 384 + ch] = wconv[u]; }
    for (int u = tid; u < 384; u += 256) bcvs[u] = bconv[u];
    __syncthreads();

    // P0b: depthwise 3x3 conv + bias + silu, straight from xin -> xcb tile
    const int hblk = (t0g & (LL - 1)) >> 7;   // uniform per block (64 tokens = half row)
    const int w0 = t0g & 127;                 // 0 or 64
#pragma unroll
    for (int k = 0; k < 12; k++) {
        int u = tid + k * 256;
        int t = u / 48, c8 = u % 48;
        long tk = t0g + t;
        float acc[8];
        float4 b0 = *(const float4*)(bcvs + c8 * 8);
        float4 b1 = *(const float4*)(bcvs + c8 * 8 + 4);
        acc[0] = b0.x; acc[1] = b0.y; acc[2] = b0.z; acc[3] = b0.w;
        acc[4] = b1.x; acc[5] = b1.y; acc[6] = b1.z; acc[7] = b1.w;
#pragma unroll
        for (int dy = -1; dy <= 1; dy++) {
            int h2 = hblk + dy;
            if (h2 < 0 || h2 >= HH) continue;   // block-uniform branch
#pragma unroll
            for (int dx = -1; dx <= 1; dx++) {
                int w2 = w0 + t + dx;
                if (w2 < 0 || w2 >= WW) continue;
                bf16x8 v = *(const bf16x8*)(xin + (tk + dy * WW + dx) * (long)DI + c8 * 8);
                const float* wp = &wcvs[((dy + 1) * 3 + (dx + 1)) * 384 + c8 * 8];
#pragma unroll
                for (int j = 0; j < 8; j++) acc[j] += (float)v[j] * wp[j];
            }
        }
        bf16x8 r;
#pragma unroll
        for (int j = 0; j < 8; j++) r[j] = (__bf16)silu_f(acc[j]);
        *(bf16x8*)(&xcb[t * 392 + c8 * 8]) = r;
    }
    __syncthreads();

    // P2: x_ssm = xc @ w_x (K=384, N=32); bc = sum_s B*C; stash B_ssm bf16
    {
        f32x4 aB = {0.f, 0.f, 0.f, 0.f}, aC = {0.f, 0.f, 0.f, 0.f};
#pragma unroll
        for (int ks = 0; ks < 12; ks++) {
            bf16x8 a = *(const bf16x8*)(&xcb[(wv * 16 + lq) * 392 + ks * 32 + quad * 8]);
            bf16x8 b0 = *(const bf16x8*)(wtx + lq * 384 + ks * 32 + quad * 8);
            bf16x8 b1 = *(const bf16x8*)(wtx + (16 + lq) * 384 + ks * 32 + quad * 8);
            aB = mfma16(a, b0, aB);
            aC = mfma16(a, b1, aC);
        }
        float p0 = aB[0] * aC[0], p1 = aB[1] * aC[1], p2 = aB[2] * aC[2], p3 = aB[3] * aC[3];
#pragma unroll
        for (int m = 1; m < 16; m <<= 1) {
            p0 += __shfl_xor(p0, m, 64);
            p1 += __shfl_xor(p1, m, 64);
            p2 += __shfl_xor(p2, m, 64);
            p3 += __shfl_xor(p3, m, 64);
        }
        int trow = wv * 16 + quad * 4;
        if (lq == 0) { bcarr[trow] = p0; bcarr[trow + 1] = p1; bcarr[trow + 2] = p2; bcarr[trow + 3] = p3; }
        bss[(trow + 0) * 24 + lq] = (__bf16)aB[0];
        bss[(trow + 1) * 24 + lq] = (__bf16)aB[1];
        bss[(trow + 2) * 24 + lq] = (__bf16)aB[2];
        bss[(trow + 3) * 24 + lq] = (__bf16)aB[3];
    }
    __syncthreads();

    bf16x8 zero8;
#pragma unroll
    for (int j = 0; j < 8; j++) zero8[j] = (__bf16)0.f;

    // A-fragments for dt MFMA (K=16 lives in quads 0,1; quads 2,3 feed zeros)
    bf16x8 aA[4];
#pragma unroll
    for (int mt = 0; mt < 4; mt++)
        aA[mt] = (quad < 2) ? *(const bf16x8*)(&bss[(mt * 16 + lq) * 24 + quad * 8]) : zero8;

    float s1 = 0.f, s2 = 0.f;

#pragma unroll
    for (int h = 0; h < 2; h++) {
        // P3a: dt MFMA for channels h*192 .. h*192+191 (3 n-tiles per wave)
        f32x4 dacc[3][4];
        float bdtv[3];
#pragma unroll
        for (int j = 0; j < 3; j++) {
            int chg = h * 192 + (wv * 3 + j) * 16 + lq;
            bf16x8 bf = (quad < 2) ? *(const bf16x8*)(wtdt + (long)chg * 16 + quad * 8) : zero8;
            bdtv[j] = bdt[chg];
#pragma unroll
            for (int mt = 0; mt < 4; mt++) {
                f32x4 z4 = {0.f, 0.f, 0.f, 0.f};
                dacc[j][mt] = mfma16(aA[mt], bf, z4);
            }
        }
        // scatter dt(+b_dt) to LDS (stride 200 -> conflict-free)
#pragma unroll
        for (int j = 0; j < 3; j++)
#pragma unroll
            for (int mt = 0; mt < 4; mt++)
#pragma unroll
                for (int r = 0; r < 4; r++)
                    dts[(mt * 16 + quad * 4 + r) * 200 + (wv * 3 + j) * 16 + lq] =
                        (__bf16)(dacc[j][mt][r] + bdtv[j]);
        __syncthreads();

        // epilogue: y = (softplus(dt)*bc + xc*dskip) * z ; accumulate LN stats
#pragma unroll
        for (int g = 0; g < 6; g++) {
            const int chl = part * 48 + g * 8;
            const int chg = h * 192 + chl;
            bf16x8 d8 = *(const bf16x8*)(&dts[te * 200 + chl]);
            bf16x8 xc8 = *(const bf16x8*)(&xcb[te * 392 + chg]);
            bf16x8 z8 = zpre[h * 6 + g];
            float4 d0 = *(const float4*)(dskip + chg);
            float4 d1 = *(const float4*)(dskip + chg + 4);
            float ds[8] = {d0.x, d0.y, d0.z, d0.w, d1.x, d1.y, d1.z, d1.w};
            const float bcv = bcarr[te];
#pragma unroll
            for (int j = 0; j < 8; j++) {
                float dtv = softplus_fast((float)d8[j]);
                float yv = (dtv * bcv + (float)xc8[j] * ds[j]) * (float)z8[j];
                s1 += yv; s2 += yv * yv;
                xc8[j] = (__bf16)yv;
            }
            *(bf16x8*)(&xcb[te * 392 + chg]) = xc8;
        }
        __syncthreads();  // dts reads done before next half's scatter
    }

    // LN (thread owns its 12 channel-groups across both halves)
    {
        s1 += __shfl_xor(s1, 1, 64); s2 += __shfl_xor(s2, 1, 64);
        s1 += __shfl_xor(s1, 2, 64); s2 += __shfl_xor(s2, 2, 64);
        float mu = s1 * (1.f / 384.f);
        float var = s2 * (1.f / 384.f) - mu * mu;
        float rstd = rsqrtf(var + 1e-5f);
#pragma unroll
        for (int gg = 0; gg < 12; gg++) {
            const int h2 = gg / 6, g6 = gg % 6;
            const int ch = h2 * 192 + part * 48 + g6 * 8;
            bf16x8 v = *(const bf16x8*)(&xcb[te * 392 + ch]);
            float4 g0 = *(const float4*)(gamma + ch);
            float4 g1 = *(const float4*)(gamma + ch + 4);
            float4 be0 = *(const float4*)(beta + ch);
            float4 be1 = *(const float4*)(beta + ch + 4);
            float gm[8] = {g0.x, g0.y, g0.z, g0.w, g1.x, g1.y, g1.z, g1.w};
            float bt[8] = {be0.x, be0.y, be0.z, be0.w, be1.x, be1.y, be1.z, be1.w};
#pragma unroll
            for (int j = 0; j < 8; j++) v[j] = (__bf16)(((float)v[j] - mu) * rstd * gm[j] + bt[j]);
            *(bf16x8*)(&xcb[te * 392 + ch]) = v;
        }
    }
    __syncthreads();

    // P5: out GEMM y[64,384] @ wt_out^T -> [64,192]; waves split N (3 n-tiles each)
    {
        f32x4 acc[3][4];
#pragma unroll
        for (int j = 0; j < 3; j++)
#pragma unroll
            for (int mt = 0; mt < 4; mt++) acc[j][mt] = (f32x4){0.f, 0.f, 0.f, 0.f};
#pragma unroll
        for (int ks = 0; ks < 12; ks++) {
            bf16x8 bfr[3];
#pragma unroll
            for (int j = 0; j < 3; j++) {
                int c = (wv * 3 + j) * 16 + lq;
                bfr[j] = *(const bf16x8*)(wtout + (long)c * 384 + ks * 32 + quad * 8);
            }
#pragma unroll
            for (int mt = 0; mt < 4; mt++) {
                bf16x8 afr = *(const bf16x8*)(&xcb[(mt * 16 + lq) * 392 + ks * 32 + quad * 8]);
#pragma unroll
                for (int j = 0; j < 3; j++) acc[j][mt] = mfma16(afr, bfr[j], acc[j][mt]);
            }
        }
        __syncthreads();  // all y-reads done; otile overwrites xcb region
#pragma unroll
        for (int j = 0; j < 3; j++) {
            int c = (wv * 3 + j) * 16 + lq;
#pragma unroll
            for (int mt = 0; mt < 4; mt++)
#pragma unroll
                for (int r = 0; r < 4; r++)
                    otile[c * 68 + mt * 16 + quad * 4 + r] = acc[j][mt][r];
        }
    }
    __syncthreads();

    // P6: store out[b][c][l]: 256 B contiguous per channel
    {
        const int bimg = t0g >> 14;
        const int l0 = t0g & (LL - 1);
#pragma unroll
        for (int k = 0; k < 12; k++) {
            int u = tid + k * 256;       // 3072 units = 192 ch x 16 float4
            int c = u >> 4, j = u & 15;
            float4 v = *(const float4*)(&otile[c * 68 + j * 4]);
            *(float4*)(out + ((long)(bimg * CC + c)) * LL + l0 + j * 4) = v;
        }
    }
}

// ---------- launch ----------
extern "C" void kernel_launch(void* const* d_in, const int* in_sizes, int n_in,
                              void* d_out, int out_size, void* d_ws, size_t ws_size,
                              hipStream_t stream) {
    (void)in_sizes; (void)n_in; (void)out_size; (void)ws_size;
    const float* x      = (const float*)d_in[0];
    const float* w_in   = (const float*)d_in[1];
    const float* w_conv = (const float*)d_in[2];
    const float* b_conv = (const float*)d_in[3];
    const float* w_x    = (const float*)d_in[4];
    const float* w_dt   = (const float*)d_in[5];
    const float* b_dt   = (const float*)d_in[6];
    const float* D_skip = (const float*)d_in[7];
    const float* w_out  = (const float*)d_in[8];
    const float* gamma  = (const float*)d_in[9];
    const float* beta   = (const float*)d_in[10];
    float* out = (float*)d_out;

    char* ws = (char*)d_ws;
    __bf16* wt_in  = (__bf16*)(ws);                       // 294912 B
    __bf16* wt_x   = (__bf16*)(ws + 294912);              // 24576 B
    __bf16* wt_dt  = (__bf16*)(ws + 319488);              // 12288 B
    __bf16* wt_out = (__bf16*)(ws + 331776);              // 147456 B
    __bf16* xin    = (__bf16*)(ws + 479232);              // 100663296 B
    __bf16* zsb    = (__bf16*)(ws + 479232 + 100663296);  // 100663296 B

    k0_prep<<<96, 256, 0, stream>>>(w_in, w_x, w_dt, w_out, wt_in, wt_x, wt_dt, wt_out);
    k1_proj<<<1024, 256, 0, stream>>>(x, wt_in, xin, zsb);
    k3_ssm<<<2048, 256, 0, stream>>>(xin, zsb, wt_x, wt_dt, wt_out, w_conv, b_conv,
                                     b_dt, D_skip, gamma, beta, out);
}